// Round 19
// baseline (107.218 us; speedup 1.0000x reference)
//
#include <hip/hip_runtime.h>
#include <hip/hip_bf16.h>

#define BSZ 2
#define SEQ 2048
#define DIN 1024
#define EMB 1024
#define NH  16
#define HD  64
#define QKV3 3072

typedef short bf16x8 __attribute__((ext_vector_type(8)));
typedef short bf16x4 __attribute__((ext_vector_type(4)));
typedef float f32x4  __attribute__((ext_vector_type(4)));
typedef float f32x8  __attribute__((ext_vector_type(8)));
typedef float f32x16 __attribute__((ext_vector_type(16)));
typedef unsigned int u32;

#define CSCL 0.18033688f   // 0.125 * log2(e)

__device__ __forceinline__ unsigned short f2bf(float f) {
    union { float f; unsigned int u; } v; v.f = f;
    unsigned int r = v.u + 0x7fffu + ((v.u >> 16) & 1u);   // RNE
    return (unsigned short)(r >> 16);
}

__device__ __forceinline__ unsigned cvt_pk_bf16(float lo, float hi) {
    unsigned r;
    asm("v_cvt_pk_bf16_f32 %0, %1, %2" : "=v"(r) : "v"(lo), "v"(hi));
    return r;
}

// async global -> LDS, 16 B per lane; lds base must be wave-uniform
__device__ __forceinline__ void gload16(const unsigned short* g, short* lds) {
    __builtin_amdgcn_global_load_lds(
        (const __attribute__((address_space(1))) u32*)g,
        (__attribute__((address_space(3))) u32*)lds, 16, 0, 0);
}

// counted-vmcnt gate (attn): tile's loads landed, next tile's stay in flight
#define GATE_VM4() do { \
    asm volatile("s_waitcnt vmcnt(4)" ::: "memory"); \
    __builtin_amdgcn_s_barrier(); \
    __builtin_amdgcn_sched_barrier(0); } while (0)
#define GATE_VM0() do { \
    asm volatile("s_waitcnt vmcnt(0)" ::: "memory"); \
    __builtin_amdgcn_s_barrier(); \
    __builtin_amdgcn_sched_barrier(0); } while (0)
#define POST_COMPUTE_BARRIER() do { \
    asm volatile("s_waitcnt lgkmcnt(0)" ::: "memory"); \
    __builtin_amdgcn_sched_barrier(0); \
    __builtin_amdgcn_s_barrier(); \
    __builtin_amdgcn_sched_barrier(0); } while (0)

// ---------------------------------------------------------------------------
// Fused fp32->bf16 conversion via v_cvt_pk_bf16_f32 (1 op / 2 elems):
// x | W_qkv (Q-rows pre-scaled by CSCL) | W_out | b_qkv
// ---------------------------------------------------------------------------
#define NX  (BSZ * SEQ * DIN)     // 4194304
#define NWQ (QKV3 * DIN)          // 3145728
#define NWO (EMB * EMB)           // 1048576
#define NTOT (NX + NWQ + NWO + QKV3)

__device__ __forceinline__ bf16x8 pk8(float4 a, float4 b) {
    union { u32 u[4]; bf16x8 v; } o;
    o.u[0] = cvt_pk_bf16(a.x, a.y);
    o.u[1] = cvt_pk_bf16(a.z, a.w);
    o.u[2] = cvt_pk_bf16(b.x, b.y);
    o.u[3] = cvt_pk_bf16(b.z, b.w);
    return o.v;
}

__global__ __launch_bounds__(256) void convert_all(
    const float* __restrict__ x, const float* __restrict__ Wq,
    const float* __restrict__ Wo, const float* __restrict__ bq,
    unsigned short* __restrict__ xb, unsigned short* __restrict__ wqb,
    unsigned short* __restrict__ wob, float* __restrict__ bqs)
{
    int i8 = (blockIdx.x * 256 + threadIdx.x) * 8;
    if (i8 >= NTOT) return;
    if (i8 < NX) {
        float4 a = *(const float4*)(x + i8);
        float4 b = *(const float4*)(x + i8 + 4);
        *(bf16x8*)(xb + i8) = pk8(a, b);
    } else if (i8 < NX + NWQ) {
        int i = i8 - NX;
        int row = i >> 10;
        float sc = ((row % 192) < 64) ? CSCL : 1.0f;
        float4 a = *(const float4*)(Wq + i);
        float4 b = *(const float4*)(Wq + i + 4);
        a.x *= sc; a.y *= sc; a.z *= sc; a.w *= sc;
        b.x *= sc; b.y *= sc; b.z *= sc; b.w *= sc;
        *(bf16x8*)(wqb + i) = pk8(a, b);
    } else if (i8 < NX + NWQ + NWO) {
        int i = i8 - NX - NWQ;
        float4 a = *(const float4*)(Wo + i);
        float4 b = *(const float4*)(Wo + i + 4);
        *(bf16x8*)(wob + i) = pk8(a, b);
    } else {
        int i = i8 - NX - NWQ - NWO;
        #pragma unroll
        for (int j = 0; j < 8; ++j) {
            float v = bq[i + j];
            if (((i + j) % 192) < 64) v *= CSCL;
            bqs[i + j] = v;
        }
    }
}

// ---------------------------------------------------------------------------
// bf16 MFMA GEMM (NT): C = A @ W^T + bias. 128x128 tile, BK=64, 4 waves.
// R10-proven single-buffer structure (32 KB LDS -> 3 blocks/CU).
// global_load_lds staging into [128][64] LDS with chunk-XOR swizzle.
// MODE 0: f32 out.  MODE 2: qkv epilogue — Q cols normal bf16, K cols
// chunk-swizzled bf16 (stored[row][c^(row&7)]); V cols written transposed
// into vtg[b][h][d][tile*128 + perm(key)] matching the attn PV k-mapping.
// ---------------------------------------------------------------------------
template <int MODE>
__global__ __launch_bounds__(256) void gemm_bf16_nt(
    const unsigned short* __restrict__ A, const unsigned short* __restrict__ W,
    const float* __restrict__ bias, void* __restrict__ Cout,
    unsigned short* __restrict__ Vout,
    int M, int N, int K)
{
    __shared__ short As[128 * 64];
    __shared__ short Bs[128 * 64];

    const int tid = threadIdx.x;
    const int m0 = blockIdx.y * 128, n0 = blockIdx.x * 128;
    const int w = tid >> 6, lane = tid & 63;
    const int lg = lane >> 4, l15 = lane & 15;
    const int wr = w >> 1, wc = w & 1;

    const int rl = tid >> 3;                  // 0..31
    const int cs = (tid & 7) ^ (rl & 7);      // pre-swizzled source chunk
    const unsigned short* Ap = A + (size_t)(m0 + rl) * K + cs * 8;
    const unsigned short* Wp = W + (size_t)(n0 + rl) * K + cs * 8;

    f32x4 acc[4][4] = {};

    for (int k0 = 0; k0 < K; k0 += 64) {
        #pragma unroll
        for (int i = 0; i < 4; ++i) {
            gload16(Ap + k0 + (size_t)(i * 32) * K, As + i * 2048 + w * 512);
            gload16(Wp + k0 + (size_t)(i * 32) * K, Bs + i * 2048 + w * 512);
        }
        __syncthreads();

        #pragma unroll
        for (int kc = 0; kc < 2; ++kc) {
            bf16x8 af[4], bfr[4];
            #pragma unroll
            for (int mf = 0; mf < 4; ++mf) {
                int row = wr * 64 + mf * 16 + l15;
                af[mf] = *(const bf16x8*)&As[row * 64 + ((((kc << 2) | lg) ^ (l15 & 7)) << 3)];
            }
            #pragma unroll
            for (int nf = 0; nf < 4; ++nf) {
                int row = wc * 64 + nf * 16 + l15;
                bfr[nf] = *(const bf16x8*)&Bs[row * 64 + ((((kc << 2) | lg) ^ (l15 & 7)) << 3)];
            }
            #pragma unroll
            for (int mf = 0; mf < 4; ++mf)
                #pragma unroll
                for (int nf = 0; nf < 4; ++nf)
                    acc[mf][nf] = __builtin_amdgcn_mfma_f32_16x16x32_bf16(
                        af[mf], bfr[nf], acc[mf][nf], 0, 0, 0);
        }
        __syncthreads();
    }

    #pragma unroll
    for (int nf = 0; nf < 4; ++nf) {
        int colbase = n0 + wc * 64 + nf * 16;
        int col = colbase + l15;
        float bv = bias[col];
        int sect = (MODE == 2) ? ((colbase % 192) / 64) : 0;
        if (MODE == 2 && sect == 2) {
            // ---- V: write into vtg with the attn PV k-permutation ----
            int h = colbase / 192;
            int dd = (colbase % 192) - 128 + l15;    // 0..63
            #pragma unroll
            for (int mf = 0; mf < 4; ++mf) {
                int row = m0 + wr * 64 + mf * 16 + lg * 4;   // rows row..row+3
                int bz = row >> 11, sl = row & 2047;
                int T = sl >> 7;
                int chunk = ((((sl >> 5) & 3) * 2 + ((sl >> 4) & 1)) << 1) | (lg & 1);
                int ci = chunk ^ (dd & 15);
                int j0 = (lg >> 1) * 4;
                bf16x4 p;
                #pragma unroll
                for (int r = 0; r < 4; ++r)
                    p[r] = (short)f2bf(acc[mf][nf][r] + bv);
                *(bf16x4*)&Vout[((size_t)(bz * NH + h) * HD + dd) * SEQ
                                + T * 128 + ci * 8 + j0] = p;
            }
        } else {
            bool isK = (MODE == 2) && (sect == 1);
            #pragma unroll
            for (int mf = 0; mf < 4; ++mf) {
                #pragma unroll
                for (int r = 0; r < 4; ++r) {
                    int row = m0 + wr * 64 + mf * 16 + lg * 4 + r;
                    float v = acc[mf][nf][r] + bv;
                    if (MODE == 0) {
                        ((float*)Cout)[(size_t)row * N + col] = v;
                    } else {
                        int scol2 = col;
                        if (isK) {
                            int cc = (col >> 3) & 7;
                            scol2 = col + (((cc ^ (row & 7)) - cc) << 3);
                        }
                        ((unsigned short*)Cout)[(size_t)row * N + scol2] = f2bf(v);
                    }
                }
            }
        }
    }
}

// ---------------------------------------------------------------------------
// MFMA flash attention, 2x K/V-fragment reuse WITH proper VGPR budget
// (launch_bounds(512,1): R14's failure was the 128-VGPR pin -> spills).
// 512 thr = 8 waves = 4 pairs; pair owns 64 q-rows (2 subtiles j=0,1 of 32);
// parity p key-splits the 128-key tile. Each K/V b128 read feeds 2 MFMAs ->
// per-CU LDS reads halved. No online max (additive partials); counted-vmcnt
// tile gates; pair-combine via LDS aliased onto the dead K/V buffers.
// ---------------------------------------------------------------------------
__global__ __launch_bounds__(512, 1) void attn_mfma(
    const unsigned short* __restrict__ qkvb,
    const unsigned short* __restrict__ vtg,
    unsigned short* __restrict__ attnb)
{
    __shared__ short Ks[2 * 128 * 64];   // dbuf K tiles; combine: pairs 0,1
    __shared__ short VT[2 * 64 * 128];   // dbuf V^T tiles; combine: pairs 2,3
    __shared__ float Cl[4][2][64];       // pair-combine: partial l

    const int tid = threadIdx.x;
    const int fl = blockIdx.x;
    const int swz = ((fl & 7) << 5) | (fl >> 3);   // bijective, 256 blocks
    const int qt = swz & 7, h = (swz >> 3) & 15, b = swz >> 7;

    const int w = tid >> 6, lane = tid & 63;
    const int l31 = lane & 31, hi = lane >> 5;
    const int pair = w >> 1, p = w & 1;

    const int row0 = b * SEQ + qt * 256;
    const int colq = h * 192, colk = colq + 64;

    // Q frags for 2 subtiles: q = row0 + pair*64 + j*32 + l31 (CSCL-scaled)
    bf16x8 qa0[4], qa1[4];
    {
        const unsigned short* qp0 =
            qkvb + (size_t)(row0 + pair * 64 + l31) * QKV3 + colq + hi * 8;
        const unsigned short* qp1 = qp0 + (size_t)32 * QKV3;
        #pragma unroll
        for (int kc = 0; kc < 4; ++kc) {
            qa0[kc] = *(const bf16x8*)(qp0 + 16 * kc);
            qa1[kc] = *(const bf16x8*)(qp1 + 16 * kc);
        }
    }

    // staging bases (512 thr: K rows tid>>3 (+64/issue), V d tid>>4 (+32))
    const unsigned short* kg = qkvb + (size_t)(b * SEQ + (tid >> 3)) * QKV3
                                    + colk + (tid & 7) * 8;
    const unsigned short* vg = vtg + ((size_t)(b * NH + h) * HD + (tid >> 4)) * SEQ
                                   + (tid & 15) * 8;

    // hoisted lane-constant LDS read offsets (shorts)
    int koff[4], voff[4];
    #pragma unroll
    for (int kc = 0; kc < 4; ++kc)
        koff[kc] = l31 * 64 + ((((kc << 1) | hi) ^ (l31 & 7)) << 3);
    #pragma unroll
    for (int c = 0; c < 4; ++c) {
        int j = p * 4 + c;
        voff[c] = l31 * 128 + ((((j << 1) | hi) ^ (l31 & 15)) << 3);
    }
    const int kbo0 = p ? 4096 : 0;   // this wave's key blocks: 2p, 2p+1

    f32x16 oA0 = {}, oA1 = {};   // subtile j=0: d 0-31, d 32-63
    f32x16 oB0 = {}, oB1 = {};   // subtile j=1
    f32x8  ps0 = {}, ps1 = {};   // partial l per subtile (8 wide)

    const int NT = SEQ / 128;    // 16

    auto stageKV = [&](int t) {
        short* KsW = Ks + (t & 1) * 8192 + w * 512;
        short* VtW = VT + (t & 1) * 8192 + w * 512;
        const unsigned short* kg0 = kg + (size_t)(t * 128) * QKV3;
        const unsigned short* vg0 = vg + t * 128;
        #pragma unroll
        for (int i = 0; i < 2; ++i)
            gload16(kg0 + (size_t)(i * 64) * QKV3, KsW + i * 4096);
        #pragma unroll
        for (int i = 0; i < 2; ++i)
            gload16(vg0 + (size_t)(i * 32) * SEQ, VtW + i * 4096);
    };

    stageKV(0);
    stageKV(1);

    for (int kt = 0; kt < NT; ++kt) {
        if (kt == NT - 1) { GATE_VM0(); } else { GATE_VM4(); }

        const short* KsC = Ks + (kt & 1) * 8192;
        const short* VtC = VT + (kt & 1) * 8192;

        // ---- per kb (32 keys): QK both subtiles -> exp2 -> pack -> PV ----
        __builtin_amdgcn_s_setprio(1);
        auto kb_block = [&](int kbo, int c0) {
            bf16x8 kf[4];
            #pragma unroll
            for (int kc = 0; kc < 4; ++kc)
                kf[kc] = *(const bf16x8*)&KsC[koff[kc] + kbo];
            f32x16 s0 = {}, s1 = {};
            #pragma unroll
            for (int kc = 0; kc < 4; ++kc) {
                s0 = __builtin_amdgcn_mfma_f32_32x32x16_bf16(kf[kc], qa0[kc], s0, 0, 0, 0);
                s1 = __builtin_amdgcn_mfma_f32_32x32x16_bf16(kf[kc], qa1[kc], s1, 0, 0, 0);
            }
            #pragma unroll
            for (int r = 0; r < 16; ++r) {
                s0[r] = __builtin_amdgcn_exp2f(s0[r]);
                s1[r] = __builtin_amdgcn_exp2f(s1[r]);
            }
            #pragma unroll
            for (int r = 0; r < 16; ++r) {
                ps0[r & 7] += s0[r];
                ps1[r & 7] += s1[r];
            }
            u32 wv0[8], wv1[8];
            #pragma unroll
            for (int i = 0; i < 8; ++i) {
                wv0[i] = cvt_pk_bf16(s0[2 * i], s0[2 * i + 1]);
                wv1[i] = cvt_pk_bf16(s1[2 * i], s1[2 * i + 1]);
            }
            #pragma unroll
            for (int c = 0; c < 2; ++c) {
                union { u32 u[4]; bf16x8 v; } pa0, pa1;
                #pragma unroll
                for (int i = 0; i < 4; ++i) {
                    pa0.u[i] = wv0[4 * c + i];
                    pa1.u[i] = wv1[4 * c + i];
                }
                bf16x8 v0 = *(const bf16x8*)&VtC[voff[c0 + c]];
                bf16x8 v1 = *(const bf16x8*)&VtC[voff[c0 + c] + 4096];
                oA0 = __builtin_amdgcn_mfma_f32_32x32x16_bf16(pa0.v, v0, oA0, 0, 0, 0);
                oA1 = __builtin_amdgcn_mfma_f32_32x32x16_bf16(pa0.v, v1, oA1, 0, 0, 0);
                oB0 = __builtin_amdgcn_mfma_f32_32x32x16_bf16(pa1.v, v0, oB0, 0, 0, 0);
                oB1 = __builtin_amdgcn_mfma_f32_32x32x16_bf16(pa1.v, v1, oB1, 0, 0, 0);
            }
        };
        kb_block(kbo0, 0);
        kb_block(kbo0 + 2048, 2);
        __builtin_amdgcn_s_setprio(0);

        POST_COMPUTE_BARRIER();
        if (kt + 2 < NT) stageKV(kt + 2);
    }

    // ---- per-wave partial l (q = l31, this wave's 64 keys) ----
    float lp0 = ((ps0[0] + ps0[1]) + (ps0[2] + ps0[3]))
              + ((ps0[4] + ps0[5]) + (ps0[6] + ps0[7]));
    float lp1 = ((ps1[0] + ps1[1]) + (ps1[2] + ps1[3]))
              + ((ps1[4] + ps1[5]) + (ps1[6] + ps1[7]));

    // ---- combine pair partials via LDS aliased onto dead K/V buffers ----
    float* Po = (pair < 2) ? ((float*)Ks + pair * 4096)
                           : ((float*)VT + (pair - 2) * 4096);
    if (p == 1) {
        #pragma unroll
        for (int r = 0; r < 16; ++r) {
            Po[r * 64 + lane]          = oA0[r];
            Po[(r + 16) * 64 + lane]   = oA1[r];
            Po[(r + 32) * 64 + lane]   = oB0[r];
            Po[(r + 48) * 64 + lane]   = oB1[r];
        }
        Cl[pair][0][lane] = lp0;
        Cl[pair][1][lane] = lp1;
    }
    __syncthreads();
    if (p == 0) {
        #pragma unroll
        for (int r = 0; r < 16; ++r) {
            oA0[r] += Po[r * 64 + lane];
            oA1[r] += Po[(r + 16) * 64 + lane];
            oB0[r] += Po[(r + 32) * 64 + lane];
            oB1[r] += Po[(r + 48) * 64 + lane];
        }
        lp0 += Cl[pair][0][lane];
        lp1 += Cl[pair][1][lane];
        lp0 += __shfl_xor(lp0, 32);
        lp1 += __shfl_xor(lp1, 32);

        #pragma unroll
        for (int r = 0; r < 16; ++r) {
            int qloc = (r & 3) + 8 * (r >> 2) + 4 * hi;
            float l0 = __shfl(lp0, qloc);
            float l1 = __shfl(lp1, qloc);
            float i0 = 1.0f / l0;
            float i1 = 1.0f / l1;
            size_t g0 = (size_t)(row0 + pair * 64 + qloc) * EMB + h * HD;
            size_t g1 = g0 + (size_t)32 * EMB;
            attnb[g0 + l31]      = f2bf(oA0[r] * i0);
            attnb[g0 + 32 + l31] = f2bf(oA1[r] * i0);
            attnb[g1 + l31]      = f2bf(oB0[r] * i1);
            attnb[g1 + 32 + l31] = f2bf(oB1[r] * i1);
        }
    }
}

// ---------------------------------------------------------------------------
extern "C" void kernel_launch(void* const* d_in, const int* in_sizes, int n_in,
                              void* d_out, int out_size, void* d_ws, size_t ws_size,
                              hipStream_t stream) {
    const float* x     = (const float*)d_in[0];
    const float* W_qkv = (const float*)d_in[1];
    const float* b_qkv = (const float*)d_in[2];
    const float* W_out = (const float*)d_in[3];
    const float* b_out = (const float*)d_in[4];
    float* out = (float*)d_out;

    // ws: xb 8M | wqkvb 6M | woutb 2M | qkvb 24M | attnb 8M | vtg 8M | bqs 12K
    char* ws = (char*)d_ws;
    unsigned short* xb     = (unsigned short*)(ws);
    unsigned short* wqkvb  = (unsigned short*)(ws + (8u << 20));
    unsigned short* woutb  = (unsigned short*)(ws + (14u << 20));
    unsigned short* qkvb   = (unsigned short*)(ws + (16u << 20));
    unsigned short* attnb  = (unsigned short*)(ws + (40u << 20));
    unsigned short* vtg    = (unsigned short*)(ws + (48u << 20));
    float*          bqs    = (float*)(ws + (56u << 20));

    const int M = BSZ * SEQ;            // 4096

    convert_all<<<(NTOT / 8 + 255) / 256, 256, 0, stream>>>(
        x, W_qkv, W_out, b_qkv, xb, wqkvb, woutb, bqs);

    gemm_bf16_nt<2><<<dim3(QKV3 / 128, M / 128), 256, 0, stream>>>(
        xb, wqkvb, bqs, qkvb, vtg, M, QKV3, DIN);

    attn_mfma<<<256, 512, 0, stream>>>(qkvb, vtg, attnb);

    gemm_bf16_nt<0><<<dim3(EMB / 128, M / 128), 256, 0, stream>>>(
        attnb, woutb, b_out, out, nullptr, M, EMB, DIN);
}